// Round 1
// baseline (41177.423 us; speedup 1.0000x reference)
//
#include <hip/hip_runtime.h>
#include <math.h>

#define BB 64
#define SS 512
#define INF 64
#define HH 512
#define G5 2560
#define TK 64

// ---------------- init: zero recurrent state ----------------
__global__ void init_kernel(float* __restrict__ p, int n) {
    int i = blockIdx.x * blockDim.x + threadIdx.x;
    if (i < n) p[i] = 0.f;
}

__device__ __forceinline__ float sigmoidf_(float v) {
    return 1.f / (1.f + __expf(-v) * 0.f + expf(-v) * 1.f);
}

// ---------------- one recurrence step (pipelined L0(t) + L1(t-1)) ----------------
// blocks 0..127   : L0, step t   (skip if t >= SS), cols j = blk*4 .. blk*4+3
// blocks 128..255 : L1, step t-1 (skip if t == 0)
__global__ __launch_bounds__(256) void step_kernel(
    const float* __restrict__ x,
    const float* __restrict__ W0, const float* __restrict__ b0v,
    const float* __restrict__ W1, const float* __restrict__ b1v,
    float* __restrict__ h0buf, float* __restrict__ h1buf,
    float* __restrict__ c0buf, float* __restrict__ c1buf,
    float* __restrict__ lstm_out, int t)
{
    __shared__ float A_lds[64 * (TK + 1)];
    __shared__ float W_lds[TK * 20];

    const int tid = threadIdx.x;
    const int b   = tid & 63;
    const int jj  = tid >> 6;           // 0..3
    const bool isL1 = (blockIdx.x >= 128);
    const int blk = isL1 ? (blockIdx.x - 128) : blockIdx.x;
    const int j0  = blk * 4;
    const int j   = j0 + jj;            // 0..511

    const float* W  = isL1 ? W1 : W0;
    const int K     = isL1 ? 1024 : 576;

    if (!isL1 && t >= SS) return;
    if (isL1 && t == 0) return;

    const int tm1 = t - 1;
    const float* h0prev = h0buf + ((t + 1) & 1) * (BB * HH);   // h0(t-1) for L0
    const float* h0cur  = h0buf + ((tm1) & 1) * (BB * HH);     // h0(t-1) for L1
    const float* h1prev = h1buf + ((tm1 + 1) & 1) * (BB * HH); // h1(t-2) for L1

    float acc0 = 0.f, acc1 = 0.f, acc2 = 0.f, acc3 = 0.f, acc4 = 0.f;

    for (int k0 = 0; k0 < K; k0 += TK) {
        __syncthreads();
        // stage A tile [64 rows][TK k]  (pad +1 to kill bank conflicts)
        for (int e = tid; e < 64 * TK; e += 256) {
            int bl = e >> 6, kl = e & 63;
            int k = k0 + kl;
            float v;
            if (!isL1) {
                v = (k < INF) ? x[(bl * SS + t) * INF + k]
                              : h0prev[bl * HH + (k - INF)];
            } else {
                v = (k < HH) ? h0cur[bl * HH + k]
                             : h1prev[bl * HH + (k - HH)];
            }
            A_lds[bl * (TK + 1) + kl] = v;
        }
        // stage W tile [TK k][5 gates x 4 cols]
        {
            int kl = tid >> 2, jl = tid & 3;
            #pragma unroll
            for (int g = 0; g < 5; ++g)
                W_lds[kl * 20 + g * 4 + jl] = W[(size_t)(k0 + kl) * G5 + g * HH + j0 + jl];
        }
        __syncthreads();
        #pragma unroll 8
        for (int k = 0; k < TK; ++k) {
            float a = A_lds[b * (TK + 1) + k];
            acc0 += a * W_lds[k * 20 + 0 * 4 + jj];
            acc1 += a * W_lds[k * 20 + 1 * 4 + jj];
            acc2 += a * W_lds[k * 20 + 2 * 4 + jj];
            acc3 += a * W_lds[k * 20 + 3 * 4 + jj];
            acc4 += a * W_lds[k * 20 + 4 * 4 + jj];
        }
    }

    const float* bv = isL1 ? b1v : b0v;
    float gf = acc0 + bv[j];
    float gi = acc1 + bv[HH + j];
    float gc = acc2 + bv[2 * HH + j];
    float go = acc3 + bv[3 * HH + j];
    float ge = acc4 + bv[4 * HH + j];

    float f  = 1.f / (1.f + expf(-gf));
    float i_ = 1.f / (1.f + expf(-gi));
    float ch = tanhf(gc);
    float o  = 1.f / (1.f + expf(-go));
    float e_ = 1.f / (1.f + expf(-ge));

    if (!isL1) {
        float c = f * c0buf[b * HH + j] + i_ * ch;
        c0buf[b * HH + j] = c;
        float hl = o * tanhf(c);
        float hn = e_ * expf(hl) + (1.f - e_) * hl;
        h0buf[(t & 1) * (BB * HH) + b * HH + j] = hn;
    } else {
        float c = f * c1buf[b * HH + j] + i_ * ch;
        c1buf[b * HH + j] = c;
        float hl = o * tanhf(c);
        float hn = e_ * expf(hl) + (1.f - e_) * hl;
        h1buf[(tm1 & 1) * (BB * HH) + b * HH + j] = hn;
        lstm_out[((size_t)b * SS + tm1) * HH + j] = hn;
    }
}

// ---------------- attention epilogue, one block per batch row ----------------
__global__ __launch_bounds__(256) void attn_kernel(
    const float* __restrict__ lstm_out,
    const float* __restrict__ Wa, const float* __restrict__ ba,
    const float* __restrict__ Wfc, const float* __restrict__ bfc,
    float* __restrict__ dout)
{
    const int b = blockIdx.x;
    const int tid = threadIdx.x;
    const int lane = tid & 63;
    const int wave = tid >> 6;   // 0..3

    __shared__ float wa_s[HH];
    __shared__ float logit[SS];
    __shared__ float wred[4];

    for (int ii = tid; ii < HH; ii += 256) wa_s[ii] = Wa[ii];
    __syncthreads();

    const float* Lb = lstm_out + (size_t)b * SS * HH;

    // logits: each wave reduces full rows
    for (int tt = wave; tt < SS; tt += 4) {
        const float* row = Lb + (size_t)tt * HH;
        float s = 0.f;
        for (int jc = lane; jc < HH; jc += 64) s += row[jc] * wa_s[jc];
        #pragma unroll
        for (int off = 32; off > 0; off >>= 1) s += __shfl_down(s, off, 64);
        if (lane == 0) logit[tt] = s + ba[0];
    }
    __syncthreads();

    // softmax over SS
    float m = -1e30f;
    for (int ii = tid; ii < SS; ii += 256) m = fmaxf(m, logit[ii]);
    #pragma unroll
    for (int off = 32; off > 0; off >>= 1) m = fmaxf(m, __shfl_down(m, off, 64));
    if (lane == 0) wred[wave] = m;
    __syncthreads();
    m = fmaxf(fmaxf(wred[0], wred[1]), fmaxf(wred[2], wred[3]));
    __syncthreads();

    float ssum = 0.f;
    for (int ii = tid; ii < SS; ii += 256) {
        float e = expf(logit[ii] - m);
        logit[ii] = e;
        ssum += e;
    }
    #pragma unroll
    for (int off = 32; off > 0; off >>= 1) ssum += __shfl_down(ssum, off, 64);
    if (lane == 0) wred[wave] = ssum;
    __syncthreads();
    ssum = wred[0] + wred[1] + wred[2] + wred[3];
    float inv = 1.f / ssum;
    __syncthreads();

    for (int ii = tid; ii < SS; ii += 256) {
        float a = logit[ii] * inv;
        logit[ii] = a;
        dout[BB + (size_t)b * SS + ii] = a;   // att output
    }
    __syncthreads();

    // ctx: thread owns cols tid and tid+256
    float ctx0 = 0.f, ctx1 = 0.f;
    for (int tt = 0; tt < SS; ++tt) {
        float a = logit[tt];
        ctx0 += a * Lb[(size_t)tt * HH + tid];
        ctx1 += a * Lb[(size_t)tt * HH + tid + 256];
    }

    // out[b] = ctx . Wfc + bfc
    float p = ctx0 * Wfc[tid] + ctx1 * Wfc[tid + 256];
    #pragma unroll
    for (int off = 32; off > 0; off >>= 1) p += __shfl_down(p, off, 64);
    __syncthreads();
    if (lane == 0) wred[wave] = p;
    __syncthreads();
    if (tid == 0) dout[b] = wred[0] + wred[1] + wred[2] + wred[3] + bfc[0];
}

extern "C" void kernel_launch(void* const* d_in, const int* in_sizes, int n_in,
                              void* d_out, int out_size, void* d_ws, size_t ws_size,
                              hipStream_t stream) {
    const float* x   = (const float*)d_in[0];
    const float* W0  = (const float*)d_in[1];
    const float* b0  = (const float*)d_in[2];
    const float* W1  = (const float*)d_in[3];
    const float* b1  = (const float*)d_in[4];
    const float* Wa  = (const float*)d_in[5];
    const float* ba  = (const float*)d_in[6];
    const float* Wfc = (const float*)d_in[7];
    const float* bfc = (const float*)d_in[8];
    float* out = (float*)d_out;
    float* ws  = (float*)d_ws;

    float* h0 = ws;                         // 2*B*H
    float* h1 = h0 + 2 * BB * HH;           // 2*B*H
    float* c0 = h1 + 2 * BB * HH;           // B*H
    float* c1 = c0 + BB * HH;               // B*H
    float* lstm = c1 + BB * HH;             // B*S*H (64 MB)

    const int state_n = 6 * BB * HH;
    init_kernel<<<(state_n + 255) / 256, 256, 0, stream>>>(ws, state_n);

    for (int t = 0; t <= SS; ++t) {
        step_kernel<<<256, 256, 0, stream>>>(x, W0, b0, W1, b1,
                                             h0, h1, c0, c1, lstm, t);
    }

    attn_kernel<<<BB, 256, 0, stream>>>(lstm, Wa, ba, Wfc, bfc, out);
}

// Round 2
// 32017.300 us; speedup vs baseline: 1.2861x; 1.2861x over previous
//
#include <hip/hip_runtime.h>
#include <math.h>

#define BB 64
#define SS 512
#define INF 64
#define HH 512
#define G5 2560
#define TK 64
#define ASTR 76   // A_lds row stride in floats (16B-aligned, conflict-free b128)
#define WSTR 68   // W_lds row stride in floats

// ---------------- init: zero recurrent state ----------------
__global__ void init_kernel(float* __restrict__ p, int n) {
    int i = blockIdx.x * blockDim.x + threadIdx.x;
    if (i < n) p[i] = 0.f;
}

// ---------------- one recurrence step (pipelined L0(t) + L1(t-1)) ----------------
// blocks 0..127   : L0, step t   (skip if t >= SS), j-cols blk*4..blk*4+3
// blocks 128..255 : L1, step t-1 (skip if t == 0)
__global__ __launch_bounds__(256) void step_kernel(
    const float* __restrict__ x,
    const float* __restrict__ W0, const float* __restrict__ b0v,
    const float* __restrict__ W1, const float* __restrict__ b1v,
    float* __restrict__ h0buf, float* __restrict__ h1buf,
    float* __restrict__ c0buf, float* __restrict__ c1buf,
    float* __restrict__ lstm_out, int t)
{
    __shared__ float A_lds[2][64 * ASTR];
    __shared__ float W_lds[2][20 * WSTR];

    const int tid  = threadIdx.x;
    const int row  = tid & 63;          // lane = batch row
    const int cw   = tid >> 6;          // wave id = j within block (0..3)
    const bool isL1 = (blockIdx.x >= 128);
    const int blk  = isL1 ? (blockIdx.x - 128) : blockIdx.x;
    const int j0   = blk * 4;
    const int j    = j0 + cw;           // 0..511

    if (!isL1 && t >= SS) return;
    if (isL1 && t == 0) return;

    const int tm1 = t - 1;
    const float* h0prev = h0buf + ((t + 1) & 1) * (BB * HH);   // h0(t-1) for L0
    const float* h0cur  = h0buf + ((tm1) & 1) * (BB * HH);     // h0(t-1) for L1
    const float* h1prev = h1buf + ((tm1 + 1) & 1) * (BB * HH); // h1(t-2) for L1

    const float* W = isL1 ? W1 : W0;
    const int NC   = isL1 ? 16 : 9;     // 64-k chunks

    // staging thread-map: A: rows i*16+(tid>>4), k-quad tid&15 ; W: kl=tid>>2, jl=tid&3
    const int sr  = tid >> 4;           // 0..15
    const int skq = (tid & 15) * 4;     // k offset within chunk (quad)
    const int kl  = tid >> 2;           // 0..63
    const int jl  = tid & 3;

    float4 ra[4];
    float  rw[5];

    // ---- prefetch chunk 0 ----
    {
        const int c = 0;
        #pragma unroll
        for (int i = 0; i < 4; ++i) {
            int r = i * 16 + sr;
            const float* src;
            int col;
            if (!isL1) {
                src = x; col = (r * SS + t) * INF + skq;          // chunk0 = x
            } else {
                src = h0cur; col = r * HH + skq;                  // chunk0 = h0cur
            }
            ra[i] = *(const float4*)(src + col);
        }
        int kg = c * TK + kl;
        #pragma unroll
        for (int g = 0; g < 5; ++g)
            rw[g] = W[(size_t)kg * G5 + g * HH + j0 + jl];
    }

    float acc0 = 0.f, acc1 = 0.f, acc2 = 0.f, acc3 = 0.f, acc4 = 0.f;
    int buf = 0;

    for (int c = 0; c < NC; ++c) {
        // ---- commit regs -> LDS (chunk c) ----
        #pragma unroll
        for (int i = 0; i < 4; ++i) {
            int r = i * 16 + sr;
            *(float4*)&A_lds[buf][r * ASTR + skq] = ra[i];
        }
        #pragma unroll
        for (int g = 0; g < 5; ++g)
            W_lds[buf][(g * 4 + jl) * WSTR + kl] = rw[g];
        __syncthreads();

        // ---- prefetch chunk c+1 -> regs (overlaps compute) ----
        if (c + 1 < NC) {
            const int cn = c + 1;
            #pragma unroll
            for (int i = 0; i < 4; ++i) {
                int r = i * 16 + sr;
                const float* src;
                int col;
                if (!isL1) {
                    // chunks 1..8 = h0prev cols (cn-1)*64 ..
                    src = h0prev; col = r * HH + (cn - 1) * TK + skq;
                } else if (cn < 8) {
                    src = h0cur;  col = r * HH + cn * TK + skq;
                } else {
                    src = h1prev; col = r * HH + (cn - 8) * TK + skq;
                }
                ra[i] = *(const float4*)(src + col);
            }
            int kg = cn * TK + kl;
            #pragma unroll
            for (int g = 0; g < 5; ++g)
                rw[g] = W[(size_t)kg * G5 + g * HH + j0 + jl];
        }

        // ---- compute chunk c ----
        const float4* Ap  = (const float4*)&A_lds[buf][row * ASTR];
        const float4* Wp0 = (const float4*)&W_lds[buf][(0 * 4 + cw) * WSTR];
        const float4* Wp1 = (const float4*)&W_lds[buf][(1 * 4 + cw) * WSTR];
        const float4* Wp2 = (const float4*)&W_lds[buf][(2 * 4 + cw) * WSTR];
        const float4* Wp3 = (const float4*)&W_lds[buf][(3 * 4 + cw) * WSTR];
        const float4* Wp4 = (const float4*)&W_lds[buf][(4 * 4 + cw) * WSTR];
        #pragma unroll
        for (int q = 0; q < 16; ++q) {
            float4 a = Ap[q];
            float4 w;
            w = Wp0[q];
            acc0 = fmaf(a.x, w.x, acc0); acc0 = fmaf(a.y, w.y, acc0);
            acc0 = fmaf(a.z, w.z, acc0); acc0 = fmaf(a.w, w.w, acc0);
            w = Wp1[q];
            acc1 = fmaf(a.x, w.x, acc1); acc1 = fmaf(a.y, w.y, acc1);
            acc1 = fmaf(a.z, w.z, acc1); acc1 = fmaf(a.w, w.w, acc1);
            w = Wp2[q];
            acc2 = fmaf(a.x, w.x, acc2); acc2 = fmaf(a.y, w.y, acc2);
            acc2 = fmaf(a.z, w.z, acc2); acc2 = fmaf(a.w, w.w, acc2);
            w = Wp3[q];
            acc3 = fmaf(a.x, w.x, acc3); acc3 = fmaf(a.y, w.y, acc3);
            acc3 = fmaf(a.z, w.z, acc3); acc3 = fmaf(a.w, w.w, acc3);
            w = Wp4[q];
            acc4 = fmaf(a.x, w.x, acc4); acc4 = fmaf(a.y, w.y, acc4);
            acc4 = fmaf(a.z, w.z, acc4); acc4 = fmaf(a.w, w.w, acc4);
        }
        buf ^= 1;
        __syncthreads();
    }

    // ---- epilogue: bias, gates, state update ----
    const float* bv = isL1 ? b1v : b0v;
    float gf = acc0 + bv[j];
    float gi = acc1 + bv[HH + j];
    float gc = acc2 + bv[2 * HH + j];
    float go = acc3 + bv[3 * HH + j];
    float ge = acc4 + bv[4 * HH + j];

    float f  = 1.f / (1.f + expf(-gf));
    float i_ = 1.f / (1.f + expf(-gi));
    float ch = tanhf(gc);
    float o  = 1.f / (1.f + expf(-go));
    float e_ = 1.f / (1.f + expf(-ge));

    if (!isL1) {
        float c = f * c0buf[row * HH + j] + i_ * ch;
        c0buf[row * HH + j] = c;
        float hl = o * tanhf(c);
        float hn = e_ * expf(hl) + (1.f - e_) * hl;
        h0buf[(t & 1) * (BB * HH) + row * HH + j] = hn;
    } else {
        float c = f * c1buf[row * HH + j] + i_ * ch;
        c1buf[row * HH + j] = c;
        float hl = o * tanhf(c);
        float hn = e_ * expf(hl) + (1.f - e_) * hl;
        h1buf[(tm1 & 1) * (BB * HH) + row * HH + j] = hn;
        lstm_out[((size_t)row * SS + tm1) * HH + j] = hn;
    }
}

// ---------------- attention epilogue, one block per batch row ----------------
__global__ __launch_bounds__(256) void attn_kernel(
    const float* __restrict__ lstm_out,
    const float* __restrict__ Wa, const float* __restrict__ ba,
    const float* __restrict__ Wfc, const float* __restrict__ bfc,
    float* __restrict__ dout)
{
    const int b = blockIdx.x;
    const int tid = threadIdx.x;
    const int lane = tid & 63;
    const int wave = tid >> 6;   // 0..3

    __shared__ float wa_s[HH];
    __shared__ float logit[SS];
    __shared__ float wred[4];

    for (int ii = tid; ii < HH; ii += 256) wa_s[ii] = Wa[ii];
    __syncthreads();

    const float* Lb = lstm_out + (size_t)b * SS * HH;

    for (int tt = wave; tt < SS; tt += 4) {
        const float* row = Lb + (size_t)tt * HH;
        float s = 0.f;
        for (int jc = lane; jc < HH; jc += 64) s += row[jc] * wa_s[jc];
        #pragma unroll
        for (int off = 32; off > 0; off >>= 1) s += __shfl_down(s, off, 64);
        if (lane == 0) logit[tt] = s + ba[0];
    }
    __syncthreads();

    float m = -1e30f;
    for (int ii = tid; ii < SS; ii += 256) m = fmaxf(m, logit[ii]);
    #pragma unroll
    for (int off = 32; off > 0; off >>= 1) m = fmaxf(m, __shfl_down(m, off, 64));
    if (lane == 0) wred[wave] = m;
    __syncthreads();
    m = fmaxf(fmaxf(wred[0], wred[1]), fmaxf(wred[2], wred[3]));
    __syncthreads();

    float ssum = 0.f;
    for (int ii = tid; ii < SS; ii += 256) {
        float e = expf(logit[ii] - m);
        logit[ii] = e;
        ssum += e;
    }
    #pragma unroll
    for (int off = 32; off > 0; off >>= 1) ssum += __shfl_down(ssum, off, 64);
    if (lane == 0) wred[wave] = ssum;
    __syncthreads();
    ssum = wred[0] + wred[1] + wred[2] + wred[3];
    float inv = 1.f / ssum;
    __syncthreads();

    for (int ii = tid; ii < SS; ii += 256) {
        float a = logit[ii] * inv;
        logit[ii] = a;
        dout[BB + (size_t)b * SS + ii] = a;   // att output
    }
    __syncthreads();

    float ctx0 = 0.f, ctx1 = 0.f;
    for (int tt = 0; tt < SS; ++tt) {
        float a = logit[tt];
        ctx0 += a * Lb[(size_t)tt * HH + tid];
        ctx1 += a * Lb[(size_t)tt * HH + tid + 256];
    }

    float p = ctx0 * Wfc[tid] + ctx1 * Wfc[tid + 256];
    #pragma unroll
    for (int off = 32; off > 0; off >>= 1) p += __shfl_down(p, off, 64);
    __syncthreads();
    if (lane == 0) wred[wave] = p;
    __syncthreads();
    if (tid == 0) dout[b] = wred[0] + wred[1] + wred[2] + wred[3] + bfc[0];
}

extern "C" void kernel_launch(void* const* d_in, const int* in_sizes, int n_in,
                              void* d_out, int out_size, void* d_ws, size_t ws_size,
                              hipStream_t stream) {
    const float* x   = (const float*)d_in[0];
    const float* W0  = (const float*)d_in[1];
    const float* b0  = (const float*)d_in[2];
    const float* W1  = (const float*)d_in[3];
    const float* b1  = (const float*)d_in[4];
    const float* Wa  = (const float*)d_in[5];
    const float* ba  = (const float*)d_in[6];
    const float* Wfc = (const float*)d_in[7];
    const float* bfc = (const float*)d_in[8];
    float* out = (float*)d_out;
    float* ws  = (float*)d_ws;

    float* h0 = ws;                         // 2*B*H
    float* h1 = h0 + 2 * BB * HH;           // 2*B*H
    float* c0 = h1 + 2 * BB * HH;           // B*H
    float* c1 = c0 + BB * HH;               // B*H
    float* lstm = c1 + BB * HH;             // B*S*H

    const int state_n = 6 * BB * HH;
    init_kernel<<<(state_n + 255) / 256, 256, 0, stream>>>(ws, state_n);

    for (int t = 0; t <= SS; ++t) {
        step_kernel<<<256, 256, 0, stream>>>(x, W0, b0, W1, b1,
                                             h0, h1, c0, c1, lstm, t);
    }

    attn_kernel<<<BB, 256, 0, stream>>>(lstm, Wa, ba, Wfc, bfc, out);
}

// Round 3
// 30289.575 us; speedup vs baseline: 1.3595x; 1.0570x over previous
//
#include <hip/hip_runtime.h>
#include <math.h>

#define BB 64
#define SS 512
#define INF 64
#define HH 512
#define G5 2560
#define TK 64
#define ASTR 76   // A_lds row stride in floats (16B-aligned)
#define WSTR 68   // W_lds row stride in floats

// ---------------- init: zero recurrent state ----------------
__global__ void init_kernel(float* __restrict__ p, int n) {
    int i = blockIdx.x * blockDim.x + threadIdx.x;
    if (i < n) p[i] = 0.f;
}

// ---------------- weight repack (per call; LDS-tiled transpose) ----------------
// P[(g*20 + gate*4 + c)*K + k] = W[k*G5 + gate*512 + g*4 + c]
// grid: (K/64) x 40 ; block 256
__global__ __launch_bounds__(256) void repack_kernel(
    const float* __restrict__ W, float* __restrict__ P, int K)
{
    __shared__ float tile[64][65];
    const int tid = threadIdx.x;
    const int kt = blockIdx.x;            // k-tile
    const int c0 = blockIdx.y * 64;       // col base (tile never spans a gate: 512%64==0)

    // read 64 k-rows x 64 cols (coalesced 256B per row)
    for (int e = tid; e < 64 * 16; e += 256) {
        int kr = e >> 4, cq = (e & 15) * 4;
        float4 v = *(const float4*)(W + (size_t)(kt * 64 + kr) * G5 + c0 + cq);
        tile[kr][cq + 0] = v.x; tile[kr][cq + 1] = v.y;
        tile[kr][cq + 2] = v.z; tile[kr][cq + 3] = v.w;
    }
    __syncthreads();

    const int gate  = c0 >> 9;
    const int gbase = (c0 & 511) >> 2;
    // write 64 out-rows x 64 k (coalesced 256B per row)
    for (int e = tid; e < 64 * 16; e += 256) {
        int lr = e >> 4;                  // local col 0..63
        int kq = (e & 15) * 4;
        int g  = gbase + (lr >> 2);
        int c  = lr & 3;
        int orow = g * 20 + gate * 4 + c;
        float4 v;
        v.x = tile[kq + 0][lr]; v.y = tile[kq + 1][lr];
        v.z = tile[kq + 2][lr]; v.w = tile[kq + 3][lr];
        *(float4*)(P + (size_t)orow * K + kt * 64 + kq) = v;
    }
}

// ---------------- one recurrence step (pipelined L0(t) + L1(t-1)) ----------------
// blocks 0..127   : L0, step t   (skip if t >= SS)
// blocks 128..255 : L1, step t-1 (skip if t == 0)
// col-group g = (blk&7)*16 + (blk>>3)  -> XCD-contiguous weight slices
__global__ __launch_bounds__(256) void step_kernel(
    const float* __restrict__ x,
    const float* __restrict__ P0, const float* __restrict__ b0v,
    const float* __restrict__ P1, const float* __restrict__ b1v,
    float* __restrict__ h0buf, float* __restrict__ h1buf,
    float* __restrict__ c0buf, float* __restrict__ c1buf,
    float* __restrict__ lstm_out, int t)
{
    __shared__ float A_lds[2][64 * ASTR];
    __shared__ float W_lds[2][20 * WSTR];

    const int tid  = threadIdx.x;
    const int row  = tid & 63;          // lane = batch row
    const int cw   = tid >> 6;          // wave id = j within group (0..3)
    const bool isL1 = (blockIdx.x >= 128);
    const int blk  = isL1 ? (blockIdx.x - 128) : blockIdx.x;
    const int g    = (blk & 7) * 16 + (blk >> 3);   // XCD-pinned col group
    const int j    = g * 4 + cw;        // output column 0..511

    if (!isL1 && t >= SS) return;
    if (isL1 && t == 0) return;

    const int tm1 = t - 1;
    const float* h0prev = h0buf + ((t + 1) & 1) * (BB * HH);   // h0(t-1) for L0
    const float* h0cur  = h0buf + ((tm1) & 1) * (BB * HH);     // h0(t-1) for L1
    const float* h1prev = h1buf + ((tm1 + 1) & 1) * (BB * HH); // h1(t-2) for L1

    const float* Pb = (isL1 ? P1 : P0);
    const int K     = isL1 ? 1024 : 576;
    const int NC    = K / TK;
    const float* Pg = Pb + (size_t)g * 20 * K;

    // staging maps
    const int sr  = tid >> 4;           // A: row group 0..15
    const int skq = (tid & 15) * 4;     // A: k-quad offset
    const int wr0 = tid >> 4;           // W: row 0..15
    const int wkq = (tid & 15) * 4;     // W: k-quad offset

    float4 ra[4];
    float4 rw0, rw1;

    // ---- prefetch chunk 0 ----
    {
        #pragma unroll
        for (int i = 0; i < 4; ++i) {
            int r = i * 16 + sr;
            const float* src; int col;
            if (!isL1) { src = x;     col = (r * SS + t) * INF + skq; }
            else       { src = h0cur; col = r * HH + skq; }
            ra[i] = *(const float4*)(src + col);
        }
        rw0 = *(const float4*)(Pg + (size_t)wr0 * K + wkq);
        if (tid < 64)
            rw1 = *(const float4*)(Pg + (size_t)(wr0 + 16) * K + wkq);
    }

    float acc0 = 0.f, acc1 = 0.f, acc2 = 0.f, acc3 = 0.f, acc4 = 0.f;
    int buf = 0;

    for (int c = 0; c < NC; ++c) {
        // ---- commit regs -> LDS ----
        #pragma unroll
        for (int i = 0; i < 4; ++i) {
            int r = i * 16 + sr;
            *(float4*)&A_lds[buf][r * ASTR + skq] = ra[i];
        }
        *(float4*)&W_lds[buf][wr0 * WSTR + wkq] = rw0;
        if (tid < 64)
            *(float4*)&W_lds[buf][(wr0 + 16) * WSTR + wkq] = rw1;
        __syncthreads();

        // ---- prefetch chunk c+1 ----
        if (c + 1 < NC) {
            const int cn = c + 1;
            #pragma unroll
            for (int i = 0; i < 4; ++i) {
                int r = i * 16 + sr;
                const float* src; int col;
                if (!isL1)        { src = h0prev; col = r * HH + (cn - 1) * TK + skq; }
                else if (cn < 8)  { src = h0cur;  col = r * HH + cn * TK + skq; }
                else              { src = h1prev; col = r * HH + (cn - 8) * TK + skq; }
                ra[i] = *(const float4*)(src + col);
            }
            rw0 = *(const float4*)(Pg + (size_t)wr0 * K + cn * TK + wkq);
            if (tid < 64)
                rw1 = *(const float4*)(Pg + (size_t)(wr0 + 16) * K + cn * TK + wkq);
        }

        // ---- compute chunk c ----
        const float4* Ap  = (const float4*)&A_lds[buf][row * ASTR];
        const float4* Wp0 = (const float4*)&W_lds[buf][(0 * 4 + cw) * WSTR];
        const float4* Wp1 = (const float4*)&W_lds[buf][(1 * 4 + cw) * WSTR];
        const float4* Wp2 = (const float4*)&W_lds[buf][(2 * 4 + cw) * WSTR];
        const float4* Wp3 = (const float4*)&W_lds[buf][(3 * 4 + cw) * WSTR];
        const float4* Wp4 = (const float4*)&W_lds[buf][(4 * 4 + cw) * WSTR];
        #pragma unroll
        for (int q = 0; q < 16; ++q) {
            float4 a = Ap[q];
            float4 w;
            w = Wp0[q];
            acc0 = fmaf(a.x, w.x, acc0); acc0 = fmaf(a.y, w.y, acc0);
            acc0 = fmaf(a.z, w.z, acc0); acc0 = fmaf(a.w, w.w, acc0);
            w = Wp1[q];
            acc1 = fmaf(a.x, w.x, acc1); acc1 = fmaf(a.y, w.y, acc1);
            acc1 = fmaf(a.z, w.z, acc1); acc1 = fmaf(a.w, w.w, acc1);
            w = Wp2[q];
            acc2 = fmaf(a.x, w.x, acc2); acc2 = fmaf(a.y, w.y, acc2);
            acc2 = fmaf(a.z, w.z, acc2); acc2 = fmaf(a.w, w.w, acc2);
            w = Wp3[q];
            acc3 = fmaf(a.x, w.x, acc3); acc3 = fmaf(a.y, w.y, acc3);
            acc3 = fmaf(a.z, w.z, acc3); acc3 = fmaf(a.w, w.w, acc3);
            w = Wp4[q];
            acc4 = fmaf(a.x, w.x, acc4); acc4 = fmaf(a.y, w.y, acc4);
            acc4 = fmaf(a.z, w.z, acc4); acc4 = fmaf(a.w, w.w, acc4);
        }
        buf ^= 1;
        __syncthreads();
    }

    // ---- epilogue: bias, gates, state update ----
    const float* bv = isL1 ? b1v : b0v;
    float gf = acc0 + bv[j];
    float gi = acc1 + bv[HH + j];
    float gc = acc2 + bv[2 * HH + j];
    float go = acc3 + bv[3 * HH + j];
    float ge = acc4 + bv[4 * HH + j];

    float f  = 1.f / (1.f + expf(-gf));
    float i_ = 1.f / (1.f + expf(-gi));
    float ch = tanhf(gc);
    float o  = 1.f / (1.f + expf(-go));
    float e_ = 1.f / (1.f + expf(-ge));

    if (!isL1) {
        float c = f * c0buf[row * HH + j] + i_ * ch;
        c0buf[row * HH + j] = c;
        float hl = o * tanhf(c);
        float hn = e_ * expf(hl) + (1.f - e_) * hl;
        h0buf[(t & 1) * (BB * HH) + row * HH + j] = hn;
    } else {
        float c = f * c1buf[row * HH + j] + i_ * ch;
        c1buf[row * HH + j] = c;
        float hl = o * tanhf(c);
        float hn = e_ * expf(hl) + (1.f - e_) * hl;
        h1buf[(tm1 & 1) * (BB * HH) + row * HH + j] = hn;
        lstm_out[((size_t)row * SS + tm1) * HH + j] = hn;
    }
}

// ---------------- attention epilogue, one block per batch row ----------------
__global__ __launch_bounds__(256) void attn_kernel(
    const float* __restrict__ lstm_out,
    const float* __restrict__ Wa, const float* __restrict__ ba,
    const float* __restrict__ Wfc, const float* __restrict__ bfc,
    float* __restrict__ dout)
{
    const int b = blockIdx.x;
    const int tid = threadIdx.x;
    const int lane = tid & 63;
    const int wave = tid >> 6;

    __shared__ float wa_s[HH];
    __shared__ float logit[SS];
    __shared__ float wred[4];

    for (int ii = tid; ii < HH; ii += 256) wa_s[ii] = Wa[ii];
    __syncthreads();

    const float* Lb = lstm_out + (size_t)b * SS * HH;

    for (int tt = wave; tt < SS; tt += 4) {
        const float* rowp = Lb + (size_t)tt * HH;
        float s = 0.f;
        for (int jc = lane; jc < HH; jc += 64) s += rowp[jc] * wa_s[jc];
        #pragma unroll
        for (int off = 32; off > 0; off >>= 1) s += __shfl_down(s, off, 64);
        if (lane == 0) logit[tt] = s + ba[0];
    }
    __syncthreads();

    float m = -1e30f;
    for (int ii = tid; ii < SS; ii += 256) m = fmaxf(m, logit[ii]);
    #pragma unroll
    for (int off = 32; off > 0; off >>= 1) m = fmaxf(m, __shfl_down(m, off, 64));
    if (lane == 0) wred[wave] = m;
    __syncthreads();
    m = fmaxf(fmaxf(wred[0], wred[1]), fmaxf(wred[2], wred[3]));
    __syncthreads();

    float ssum = 0.f;
    for (int ii = tid; ii < SS; ii += 256) {
        float e = expf(logit[ii] - m);
        logit[ii] = e;
        ssum += e;
    }
    #pragma unroll
    for (int off = 32; off > 0; off >>= 1) ssum += __shfl_down(ssum, off, 64);
    if (lane == 0) wred[wave] = ssum;
    __syncthreads();
    ssum = wred[0] + wred[1] + wred[2] + wred[3];
    float inv = 1.f / ssum;
    __syncthreads();

    for (int ii = tid; ii < SS; ii += 256) {
        float a = logit[ii] * inv;
        logit[ii] = a;
        dout[BB + (size_t)b * SS + ii] = a;
    }
    __syncthreads();

    float ctx0 = 0.f, ctx1 = 0.f;
    for (int tt = 0; tt < SS; ++tt) {
        float a = logit[tt];
        ctx0 += a * Lb[(size_t)tt * HH + tid];
        ctx1 += a * Lb[(size_t)tt * HH + tid + 256];
    }

    float p = ctx0 * Wfc[tid] + ctx1 * Wfc[tid + 256];
    #pragma unroll
    for (int off = 32; off > 0; off >>= 1) p += __shfl_down(p, off, 64);
    __syncthreads();
    if (lane == 0) wred[wave] = p;
    __syncthreads();
    if (tid == 0) dout[b] = wred[0] + wred[1] + wred[2] + wred[3] + bfc[0];
}

extern "C" void kernel_launch(void* const* d_in, const int* in_sizes, int n_in,
                              void* d_out, int out_size, void* d_ws, size_t ws_size,
                              hipStream_t stream) {
    const float* x   = (const float*)d_in[0];
    const float* W0  = (const float*)d_in[1];
    const float* b0  = (const float*)d_in[2];
    const float* W1  = (const float*)d_in[3];
    const float* b1  = (const float*)d_in[4];
    const float* Wa  = (const float*)d_in[5];
    const float* ba  = (const float*)d_in[6];
    const float* Wfc = (const float*)d_in[7];
    const float* bfc = (const float*)d_in[8];
    float* out = (float*)d_out;
    float* ws  = (float*)d_ws;

    float* h0   = ws;                        // 2*B*H
    float* h1   = h0 + 2 * BB * HH;          // 2*B*H
    float* c0   = h1 + 2 * BB * HH;          // B*H
    float* c1   = c0 + BB * HH;              // B*H
    float* lstm = c1 + BB * HH;              // B*S*H
    float* P0   = lstm + (size_t)BB * SS * HH;      // 2560*576
    float* P1   = P0 + (size_t)G5 * (INF + HH);     // 2560*1024

    const int state_n = 6 * BB * HH;
    init_kernel<<<(state_n + 255) / 256, 256, 0, stream>>>(ws, state_n);

    repack_kernel<<<dim3((INF + HH) / 64, 40), 256, 0, stream>>>(W0, P0, INF + HH);
    repack_kernel<<<dim3((HH + HH) / 64, 40), 256, 0, stream>>>(W1, P1, HH + HH);

    for (int t = 0; t <= SS; ++t) {
        step_kernel<<<256, 256, 0, stream>>>(x, P0, b0, P1, b1,
                                             h0, h1, c0, c1, lstm, t);
    }

    attn_kernel<<<BB, 256, 0, stream>>>(lstm, Wa, ba, Wfc, bfc, out);
}

// Round 4
// 24908.902 us; speedup vs baseline: 1.6531x; 1.2160x over previous
//
#include <hip/hip_runtime.h>
#include <math.h>

#define BB 64
#define SS 512
#define INF 64
#define HH 512
#define G5 2560

// ---------------- init: zero recurrent state ----------------
__global__ void init_kernel(float* __restrict__ p, int n) {
    int i = blockIdx.x * blockDim.x + threadIdx.x;
    if (i < n) p[i] = 0.f;
}

// ---------------- weight repack (per call; LDS-tiled transpose) ----------------
// P[(g*20 + gate*4 + c)*K + k] = W[k*G5 + gate*512 + g*4 + c]
__global__ __launch_bounds__(256) void repack_kernel(
    const float* __restrict__ W, float* __restrict__ P, int K)
{
    __shared__ float tile[64][65];
    const int tid = threadIdx.x;
    const int kt = blockIdx.x;
    const int c0 = blockIdx.y * 64;

    for (int e = tid; e < 64 * 16; e += 256) {
        int kr = e >> 4, cq = (e & 15) * 4;
        float4 v = *(const float4*)(W + (size_t)(kt * 64 + kr) * G5 + c0 + cq);
        tile[kr][cq + 0] = v.x; tile[kr][cq + 1] = v.y;
        tile[kr][cq + 2] = v.z; tile[kr][cq + 3] = v.w;
    }
    __syncthreads();

    const int gate  = c0 >> 9;
    const int gbase = (c0 & 511) >> 2;
    for (int e = tid; e < 64 * 16; e += 256) {
        int lr = e >> 4;
        int kq = (e & 15) * 4;
        int g  = gbase + (lr >> 2);
        int c  = lr & 3;
        int orow = g * 20 + gate * 4 + c;
        float4 v;
        v.x = tile[kq + 0][lr]; v.y = tile[kq + 1][lr];
        v.z = tile[kq + 2][lr]; v.w = tile[kq + 3][lr];
        *(float4*)(P + (size_t)orow * K + kt * 64 + kq) = v;
    }
}

// ---------------- one recurrence step (pipelined L0(t) + L1(t-1)) ----------------
// blocks 0..127: L0 step t ; blocks 128..255: L1 step t-1
// Each block: one col-group g (4 output cols). 4 waves split K into quarters.
// Inner loop: A from global (per-lane float4), W broadcast from global (20 rows),
// double-buffered in registers. NO LDS in the inner loop, no inner barriers.
__global__ __launch_bounds__(256) void step_kernel(
    const float* __restrict__ x,
    const float* __restrict__ P0, const float* __restrict__ b0v,
    const float* __restrict__ P1, const float* __restrict__ b1v,
    float* __restrict__ h0buf, float* __restrict__ h1buf,
    float* __restrict__ c0buf, float* __restrict__ c1buf,
    float* __restrict__ lstm_out, int t)
{
    const int tid  = threadIdx.x;
    const int lane = tid & 63;          // batch row
    const int wv   = tid >> 6;          // K-quarter id 0..3
    const bool isL1 = (blockIdx.x >= 128);
    const int blk  = isL1 ? (blockIdx.x - 128) : blockIdx.x;
    const int g    = (blk & 7) * 16 + (blk >> 3);   // XCD-pinned col group

    if (!isL1 && t >= SS) return;
    if (isL1 && t == 0) return;

    const int tm1 = t - 1;
    const float* h0prev = h0buf + ((t + 1) & 1) * (BB * HH);   // h0(t-1) for L0
    const float* h0cur  = h0buf + (tm1 & 1) * (BB * HH);       // h0(t-1) for L1
    const float* h1prev = h1buf + ((tm1 + 1) & 1) * (BB * HH); // h1(t-2) for L1

    const float* Pb = isL1 ? P1 : P0;
    const int K  = isL1 ? 1024 : 576;
    const int QK = K >> 2;              // 256 or 144 k per wave
    const int NQ = QK >> 2;             // quads: 64 or 36 (both even)
    const int k0 = wv * QK;

    const float* Pg = Pb + (size_t)g * 20 * K;
    const float* wrow[20];
    #pragma unroll
    for (int r = 0; r < 20; ++r) wrow[r] = Pg + r * K;   // uniform SGPR bases

    const float* xb = x + (lane * SS + t) * INF;   // L0 sources
    const float* hb = h0prev + (size_t)lane * HH;
    const float* aBase = isL1
        ? (((wv < 2) ? h0cur : h1prev) + (size_t)lane * HH + (k0 & 511))
        : nullptr;

    auto loadA = [&](int q) -> float4 {
        if (isL1) return *(const float4*)(aBase + 4 * q);
        int kg = k0 + 4 * q;
        const float* p = (kg < INF) ? (xb + kg) : (hb + (kg - INF));
        return *(const float4*)p;
    };
    auto loadW = [&](float4* dst, int q) {
        int kg = k0 + 4 * q;
        #pragma unroll
        for (int r = 0; r < 20; ++r) dst[r] = *(const float4*)(wrow[r] + kg);
    };

    float acc[20];
    #pragma unroll
    for (int r = 0; r < 20; ++r) acc[r] = 0.f;

    float4 wA[20], wB[20];
    float4 aA, aB;
    aA = loadA(0); loadW(wA, 0);

    for (int q = 0; q < NQ; q += 2) {
        aB = loadA(q + 1); loadW(wB, q + 1);
        #pragma unroll
        for (int r = 0; r < 20; ++r) {
            acc[r] = fmaf(aA.x, wA[r].x, acc[r]);
            acc[r] = fmaf(aA.y, wA[r].y, acc[r]);
            acc[r] = fmaf(aA.z, wA[r].z, acc[r]);
            acc[r] = fmaf(aA.w, wA[r].w, acc[r]);
        }
        if (q + 2 < NQ) { aA = loadA(q + 2); loadW(wA, q + 2); }
        #pragma unroll
        for (int r = 0; r < 20; ++r) {
            acc[r] = fmaf(aB.x, wB[r].x, acc[r]);
            acc[r] = fmaf(aB.y, wB[r].y, acc[r]);
            acc[r] = fmaf(aB.z, wB[r].z, acc[r]);
            acc[r] = fmaf(aB.w, wB[r].w, acc[r]);
        }
    }

    // ---- cross-wave K reduction (one barrier) ----
    __shared__ float red[4][20][64];
    #pragma unroll
    for (int r = 0; r < 20; ++r) red[wv][r][lane] = acc[r];
    __syncthreads();

    // wave wv finishes column c = wv of the group
    const int j = g * 4 + wv;
    const float* bv = isL1 ? b1v : b0v;
    float gv[5];
    #pragma unroll
    for (int gate = 0; gate < 5; ++gate) {
        int r = gate * 4 + wv;
        gv[gate] = red[0][r][lane] + red[1][r][lane]
                 + red[2][r][lane] + red[3][r][lane]
                 + bv[gate * HH + j];
    }

    float f  = 1.f / (1.f + expf(-gv[0]));
    float i_ = 1.f / (1.f + expf(-gv[1]));
    float ch = tanhf(gv[2]);
    float o  = 1.f / (1.f + expf(-gv[3]));
    float e_ = 1.f / (1.f + expf(-gv[4]));

    if (!isL1) {
        float c = f * c0buf[lane * HH + j] + i_ * ch;
        c0buf[lane * HH + j] = c;
        float hl = o * tanhf(c);
        float hn = e_ * expf(hl) + (1.f - e_) * hl;
        h0buf[(t & 1) * (BB * HH) + lane * HH + j] = hn;
    } else {
        float c = f * c1buf[lane * HH + j] + i_ * ch;
        c1buf[lane * HH + j] = c;
        float hl = o * tanhf(c);
        float hn = e_ * expf(hl) + (1.f - e_) * hl;
        h1buf[(tm1 & 1) * (BB * HH) + lane * HH + j] = hn;
        lstm_out[((size_t)lane * SS + tm1) * HH + j] = hn;
    }
}

// ---------------- attention epilogue, one block per batch row ----------------
__global__ __launch_bounds__(256) void attn_kernel(
    const float* __restrict__ lstm_out,
    const float* __restrict__ Wa, const float* __restrict__ ba,
    const float* __restrict__ Wfc, const float* __restrict__ bfc,
    float* __restrict__ dout)
{
    const int b = blockIdx.x;
    const int tid = threadIdx.x;
    const int lane = tid & 63;
    const int wave = tid >> 6;

    __shared__ float wa_s[HH];
    __shared__ float logit[SS];
    __shared__ float wred[4];

    for (int ii = tid; ii < HH; ii += 256) wa_s[ii] = Wa[ii];
    __syncthreads();

    const float* Lb = lstm_out + (size_t)b * SS * HH;

    for (int tt = wave; tt < SS; tt += 4) {
        const float* rowp = Lb + (size_t)tt * HH;
        float s = 0.f;
        for (int jc = lane; jc < HH; jc += 64) s += rowp[jc] * wa_s[jc];
        #pragma unroll
        for (int off = 32; off > 0; off >>= 1) s += __shfl_down(s, off, 64);
        if (lane == 0) logit[tt] = s + ba[0];
    }
    __syncthreads();

    float m = -1e30f;
    for (int ii = tid; ii < SS; ii += 256) m = fmaxf(m, logit[ii]);
    #pragma unroll
    for (int off = 32; off > 0; off >>= 1) m = fmaxf(m, __shfl_down(m, off, 64));
    if (lane == 0) wred[wave] = m;
    __syncthreads();
    m = fmaxf(fmaxf(wred[0], wred[1]), fmaxf(wred[2], wred[3]));
    __syncthreads();

    float ssum = 0.f;
    for (int ii = tid; ii < SS; ii += 256) {
        float e = expf(logit[ii] - m);
        logit[ii] = e;
        ssum += e;
    }
    #pragma unroll
    for (int off = 32; off > 0; off >>= 1) ssum += __shfl_down(ssum, off, 64);
    if (lane == 0) wred[wave] = ssum;
    __syncthreads();
    ssum = wred[0] + wred[1] + wred[2] + wred[3];
    float inv = 1.f / ssum;
    __syncthreads();

    for (int ii = tid; ii < SS; ii += 256) {
        float a = logit[ii] * inv;
        logit[ii] = a;
        dout[BB + (size_t)b * SS + ii] = a;
    }
    __syncthreads();

    float ctx0 = 0.f, ctx1 = 0.f;
    for (int tt = 0; tt < SS; ++tt) {
        float a = logit[tt];
        ctx0 += a * Lb[(size_t)tt * HH + tid];
        ctx1 += a * Lb[(size_t)tt * HH + tid + 256];
    }

    float p = ctx0 * Wfc[tid] + ctx1 * Wfc[tid + 256];
    #pragma unroll
    for (int off = 32; off > 0; off >>= 1) p += __shfl_down(p, off, 64);
    __syncthreads();
    if (lane == 0) wred[wave] = p;
    __syncthreads();
    if (tid == 0) dout[b] = wred[0] + wred[1] + wred[2] + wred[3] + bfc[0];
}

extern "C" void kernel_launch(void* const* d_in, const int* in_sizes, int n_in,
                              void* d_out, int out_size, void* d_ws, size_t ws_size,
                              hipStream_t stream) {
    const float* x   = (const float*)d_in[0];
    const float* W0  = (const float*)d_in[1];
    const float* b0  = (const float*)d_in[2];
    const float* W1  = (const float*)d_in[3];
    const float* b1  = (const float*)d_in[4];
    const float* Wa  = (const float*)d_in[5];
    const float* ba  = (const float*)d_in[6];
    const float* Wfc = (const float*)d_in[7];
    const float* bfc = (const float*)d_in[8];
    float* out = (float*)d_out;
    float* ws  = (float*)d_ws;

    float* h0   = ws;
    float* h1   = h0 + 2 * BB * HH;
    float* c0   = h1 + 2 * BB * HH;
    float* c1   = c0 + BB * HH;
    float* lstm = c1 + BB * HH;
    float* P0   = lstm + (size_t)BB * SS * HH;
    float* P1   = P0 + (size_t)G5 * (INF + HH);

    const int state_n = 6 * BB * HH;
    init_kernel<<<(state_n + 255) / 256, 256, 0, stream>>>(ws, state_n);

    repack_kernel<<<dim3((INF + HH) / 64, 40), 256, 0, stream>>>(W0, P0, INF + HH);
    repack_kernel<<<dim3((HH + HH) / 64, 40), 256, 0, stream>>>(W1, P1, HH + HH);

    for (int t = 0; t <= SS; ++t) {
        step_kernel<<<256, 256, 0, stream>>>(x, P0, b0, P1, b1,
                                             h0, h1, c0, c1, lstm, t);
    }

    attn_kernel<<<BB, 256, 0, stream>>>(lstm, Wa, ba, Wfc, bfc, out);
}